// Round 3
// baseline (646.152 us; speedup 1.0000x reference)
//
#include <hip/hip_runtime.h>
#include <math.h>

// Problem constants
static const int B_  = 4;
static const int CE_ = 128;
static const int CD_ = 256;
static const int HE_ = 256;   // = WE
static const int HD_ = 128;   // = WD
static const int N_  = 16;
#define PLANE  65536          // HE*WE = 256*256
#define DPLANE 16384          // HD*WD = 128*128
#define UPSCALE (127.0f/255.0f)

// float -> monotonic unsigned key (order-preserving, for atomicMax)
__device__ __forceinline__ unsigned fkey(float f) {
  unsigned b = __float_as_uint(f);
  return (b & 0x80000000u) ? ~b : (b | 0x80000000u);
}
__device__ __forceinline__ float fdec(unsigned k) {
  return __uint_as_float((k & 0x80000000u) ? (k & 0x7fffffffu) : ~k);
}

// ---------------------------------------------------------------------------
// Phase A: fused stats kernel. 2304 blocks x 256 threads.
//   blocks [0,1024)    : dec per-pixel stats (bilinear up2 + relu on the fly)
//   blocks [1024,2048) : dec per-channel stats over virtual upsampled plane
//   blocks [2048,2304) : enc fused: per-pixel stats (float4, 4 rows/block)
//                        + per-channel sum/max via wave reduce + atomics
// ---------------------------------------------------------------------------
__global__ __launch_bounds__(256) void k_stats(
    const float* __restrict__ xe, const float* __restrict__ xd,
    const float* __restrict__ sw1e, const float* __restrict__ sb1e,
    const float* __restrict__ sw1d, const float* __restrict__ sb1d,
    float* __restrict__ stats, float* __restrict__ eav_sum,
    unsigned* __restrict__ emx_key,
    float* __restrict__ dav, float* __restrict__ dmx) {
  __shared__ float smem[768];
  int blk = blockIdx.x;
  int t = threadIdx.x;

  if (blk < 1024) {
    // ---- dec per-pixel (up2 align_corners + relu fused) ------------------
    int b = blk >> 8, h = blk & 255;
    float bias = sb1d[0];
    smem[t] = sw1d[t];   // CD_ = 256 weights
    __syncthreads();
    float ph = (float)h * UPSCALE;
    int ih0 = (int)ph; float wh = ph - (float)ih0;
    int ih1 = min(ih0 + 1, HD_ - 1);
    float pw = (float)t * UPSCALE;
    int iw0 = (int)pw; float ww = pw - (float)iw0;
    int iw1 = min(iw0 + 1, HD_ - 1);
    float w00 = (1.f - wh) * (1.f - ww), w01 = (1.f - wh) * ww;
    float w10 = wh * (1.f - ww),        w11 = wh * ww;
    const float* xb = xd + (size_t)b * CD_ * DPLANE;
    int o00 = ih0 * HD_ + iw0, o01 = ih0 * HD_ + iw1;
    int o10 = ih1 * HD_ + iw0, o11 = ih1 * HD_ + iw1;
    float mx = -INFINITY, sm = 0.f, pj = 0.f;
#pragma unroll 4
    for (int c = 0; c < CD_; ++c) {
      const float* pc = xb + (size_t)c * DPLANE;
      float v = w00 * pc[o00] + w01 * pc[o01] + w10 * pc[o10] + w11 * pc[o11];
      v = fmaxf(v, 0.f);
      mx = fmaxf(mx, v);
      sm += v;
      pj = fmaf(v, smem[c], pj);
    }
    size_t o = (((size_t)b * 6 + 3) * HE_ + h) * (size_t)HE_ + t;
    stats[o] = mx;
    stats[o + (size_t)PLANE] = sm * (1.f / CD_);
    stats[o + 2 * (size_t)PLANE] = pj + bias;

  } else if (blk < 2048) {
    // ---- dec per-channel over virtual upsampled+relu plane ---------------
    int bc = blk - 1024;
    const float* p = xd + (size_t)bc * DPLANE;
    int*   so0  = (int*)smem;
    int*   so1  = so0 + 256;
    float* swht = smem + 512;
    {
      float ph = (float)t * UPSCALE;
      int ih0 = (int)ph;
      so0[t]  = ih0 * HD_;
      so1[t]  = min(ih0 + 1, HD_ - 1) * HD_;
      swht[t] = ph - (float)ih0;
    }
    float pw = (float)t * UPSCALE;
    int iw0 = (int)pw; float ww = pw - (float)iw0;
    int iw1 = min(iw0 + 1, HD_ - 1);
    __syncthreads();
    float sm = 0.f, m = -INFINITY;
#pragma unroll 4
    for (int hh = 0; hh < 256; ++hh) {
      const float* r0 = p + so0[hh];
      const float* r1 = p + so1[hh];
      float wh = swht[hh];
      float top = r0[iw0] * (1.f - ww) + r0[iw1] * ww;
      float bot = r1[iw0] * (1.f - ww) + r1[iw1] * ww;
      float v = fmaxf((1.f - wh) * top + wh * bot, 0.f);
      sm += v;
      m = fmaxf(m, v);
    }
    __syncthreads();   // smem reuse
    float* ss = smem;
    float* sx = smem + 256;
    ss[t] = sm; sx[t] = m;
    __syncthreads();
    for (int s = 128; s > 0; s >>= 1) {
      if (t < s) { ss[t] += ss[t + s]; sx[t] = fmaxf(sx[t], sx[t + s]); }
      __syncthreads();
    }
    if (t == 0) { dav[bc] = ss[0] * (1.f / PLANE); dmx[bc] = sx[0]; }

  } else {
    // ---- enc fused: 4 rows per block, float4 per thread ------------------
    int bb = blk - 2048;            // 0..255
    int b = bb >> 6;                // batch
    int h0 = (bb & 63) * 4;        // first row of tile
    int r = t >> 6, q = t & 63;    // row-in-tile, float4 col
    int h = h0 + r;
    float bias = sb1e[0];
    if (t < CE_) smem[t] = sw1e[t];
    __syncthreads();
    const float4* base = (const float4*)xe + (size_t)(b * CE_) * (PLANE / 4)
                         + (size_t)h * 64 + q;
    float4 mx4 = make_float4(-INFINITY, -INFINITY, -INFINITY, -INFINITY);
    float4 sm4 = make_float4(0.f, 0.f, 0.f, 0.f);
    float4 pj4 = make_float4(0.f, 0.f, 0.f, 0.f);
    float* eacc = eav_sum + b * CE_;
    unsigned* emk = emx_key + b * CE_;
#pragma unroll 4
    for (int c = 0; c < CE_; ++c) {
      float4 v = base[(size_t)c * (PLANE / 4)];
      float wc = smem[c];
      mx4.x = fmaxf(mx4.x, v.x); mx4.y = fmaxf(mx4.y, v.y);
      mx4.z = fmaxf(mx4.z, v.z); mx4.w = fmaxf(mx4.w, v.w);
      sm4.x += v.x; sm4.y += v.y; sm4.z += v.z; sm4.w += v.w;
      pj4.x = fmaf(v.x, wc, pj4.x); pj4.y = fmaf(v.y, wc, pj4.y);
      pj4.z = fmaf(v.z, wc, pj4.z); pj4.w = fmaf(v.w, wc, pj4.w);
      // per-channel row partial, reduced across the wave
      float cs = (v.x + v.y) + (v.z + v.w);
      float cm = fmaxf(fmaxf(v.x, v.y), fmaxf(v.z, v.w));
#pragma unroll
      for (int msk = 32; msk > 0; msk >>= 1) {
        cs += __shfl_xor(cs, msk);
        cm = fmaxf(cm, __shfl_xor(cm, msk));
      }
      if ((t & 63) == 0) {
        atomicAdd(&eacc[c], cs);
        atomicMax(&emk[c], fkey(cm));
      }
    }
    size_t o4 = (size_t)(b * 6) * (PLANE / 4) + (size_t)h * 64 + q;
    float4* so = (float4*)stats;
    so[o4] = mx4;
    sm4.x *= (1.f / CE_); sm4.y *= (1.f / CE_);
    sm4.z *= (1.f / CE_); sm4.w *= (1.f / CE_);
    so[o4 + PLANE / 4] = sm4;
    pj4.x += bias; pj4.y += bias; pj4.z += bias; pj4.w += bias;
    so[o4 + 2 * (PLANE / 4)] = pj4;
  }
}

// ---------------------------------------------------------------------------
// Phase B: fused SAG conv + CAG MLP + final gate.
// grid = B*256 blocks (b,row), 256 threads (col).
// ---------------------------------------------------------------------------
__global__ __launch_bounds__(256) void k_gate(
    const float* __restrict__ stats,
    const float* __restrict__ we, const float* __restrict__ be,
    const float* __restrict__ wd, const float* __restrict__ bd,
    const float* __restrict__ eav_sum, const unsigned* __restrict__ emx_key,
    const float* __restrict__ dav, const float* __restrict__ dmx,
    const float* __restrict__ cw_ea, const float* __restrict__ cb_ea,
    const float* __restrict__ cw_em, const float* __restrict__ cb_em,
    const float* __restrict__ cw_da, const float* __restrict__ cb_da,
    const float* __restrict__ cw_dm, const float* __restrict__ cb_dm,
    const float* __restrict__ cw_f, const float* __restrict__ cb_f,
    const float* __restrict__ x, float* __restrict__ out) {
  int bh = blockIdx.x;
  int b = bh >> 8, h = bh & 255;
  int t = threadIdx.x;
  int w = t;

  __shared__ float swE[147], swD[147];
  __shared__ float part[16][17];   // [n][slice], padded
  __shared__ float s_n[16];
  __shared__ float s_ch[128];
  __shared__ float s_spat[256];

  if (t < 147) { swE[t] = we[t]; swD[t] = wd[t]; }

  // ---- CAG partial dot products: thread t -> (n = t&15, slice = t>>4) ----
  {
    int n = t & 15, sl = t >> 4;
    const float* ea = eav_sum + b * CE_;
    const unsigned* ek = emx_key + b * CE_;
    const float* da = dav + b * CD_;
    const float* dm = dmx + b * CD_;
    float p = 0.f;
#pragma unroll
    for (int i = 0; i < 8; ++i) {
      int c = sl * 8 + i;
      p = fmaf(ea[c] * (1.f / PLANE), cw_ea[n * CE_ + c], p);
      p = fmaf(fdec(ek[c]), cw_em[n * CE_ + c], p);
    }
#pragma unroll
    for (int i = 0; i < 16; ++i) {
      int c = sl * 16 + i;
      p = fmaf(da[c], cw_da[n * CD_ + c], p);
      p = fmaf(dm[c], cw_dm[n * CD_ + c], p);
    }
    part[n][sl] = p;
  }
  __syncthreads();
  if (t < 16) {
    float s = cb_ea[t] + cb_em[t] + cb_da[t] + cb_dm[t];
#pragma unroll
    for (int sl = 0; sl < 16; ++sl) s += part[t][sl];
    s_n[t] = s;
  }
  __syncthreads();
  if (t < 128) {
    float s = cb_f[t];
#pragma unroll
    for (int n = 0; n < N_; ++n) s = fmaf(s_n[n], cw_f[t * N_ + n], s);
    s_ch[t] = 1.f / (1.f + __expf(-s));
  }

  // ---- SAG dual conv 7x7 over 3 stat channels each -----------------------
  float acc = be[0] + bd[0];
  const float* sb = stats + ((size_t)b * 6) * PLANE;
#pragma unroll
  for (int ic = 0; ic < 3; ++ic) {
    const float* pe = sb + (size_t)ic * PLANE;
    const float* pd = sb + (size_t)(ic + 3) * PLANE;
#pragma unroll
    for (int ky = 0; ky < 7; ++ky) {
      int y = h + ky - 3;
      if ((unsigned)y >= 256u) continue;
      const float* rowE = pe + y * 256;
      const float* rowD = pd + y * 256;
#pragma unroll
      for (int kx = 0; kx < 7; ++kx) {
        int xw = w + kx - 3;
        if ((unsigned)xw >= 256u) continue;
        float we_ = swE[ic * 49 + ky * 7 + kx];
        float wd_ = swD[ic * 49 + ky * 7 + kx];
        acc = fmaf(rowE[xw], we_, acc);
        acc = fmaf(rowD[xw], wd_, acc);
      }
    }
  }
  s_spat[w] = 1.f / (1.f + __expf(-acc));
  __syncthreads();

  // ---- final gate: out = x * spat * ch, float4 IO ------------------------
  int w4 = t & 63;     // float4 index within the 256-wide row
  int cq = t >> 6;     // channel phase 0..3 (wave-uniform)
  float4 sv = ((const float4*)s_spat)[w4];
  const float4* xp = (const float4*)x + ((size_t)b * CE_) * (PLANE / 4) + h * 64;
  float4*       op = (float4*)out     + ((size_t)b * CE_) * (PLANE / 4) + h * 64;
  for (int c = cq; c < CE_; c += 4) {
    float cv = s_ch[c];
    float4 xv = xp[(size_t)c * (PLANE / 4) + w4];
    float4 o;
    o.x = xv.x * sv.x * cv;
    o.y = xv.y * sv.y * cv;
    o.z = xv.z * sv.z * cv;
    o.w = xv.w * sv.w * cv;
    op[(size_t)c * (PLANE / 4) + w4] = o;
  }
}

// ---------------------------------------------------------------------------
extern "C" void kernel_launch(void* const* d_in, const int* in_sizes, int n_in,
                              void* d_out, int out_size, void* d_ws, size_t ws_size,
                              hipStream_t stream) {
  const float* x_enc = (const float*)d_in[0];
  const float* x_dec = (const float*)d_in[1];
  const float* cw_ea = (const float*)d_in[2];
  const float* cb_ea = (const float*)d_in[3];
  const float* cw_em = (const float*)d_in[4];
  const float* cb_em = (const float*)d_in[5];
  const float* cw_da = (const float*)d_in[6];
  const float* cb_da = (const float*)d_in[7];
  const float* cw_dm = (const float*)d_in[8];
  const float* cb_dm = (const float*)d_in[9];
  const float* cw_f  = (const float*)d_in[10];
  const float* cb_f  = (const float*)d_in[11];
  const float* sw1_e = (const float*)d_in[12];
  const float* sb1_e = (const float*)d_in[13];
  const float* sw2_e = (const float*)d_in[14];
  const float* sb2_e = (const float*)d_in[15];
  const float* sw1_d = (const float*)d_in[16];
  const float* sb1_d = (const float*)d_in[17];
  const float* sw2_d = (const float*)d_in[18];
  const float* sb2_d = (const float*)d_in[19];
  float* out = (float*)d_out;
  (void)in_sizes; (void)n_in; (void)out_size; (void)ws_size;

  // workspace layout (floats)
  float* ws    = (float*)d_ws;
  float* stats = ws;                       // B*6*PLANE = 1,572,864
  float*    eav = ws + 1572864;            // B*CE raw sums      (512)
  unsigned* emx = (unsigned*)(ws + 1573376); // B*CE max keys    (512)
  float*    dav = ws + 1573888;            // B*CD               (1024)
  float*    dmx = ws + 1574912;            // B*CD               (1024)

  // zero the enc-channel accumulators (sum=0; key=0 is the ordering identity)
  hipMemsetAsync(eav, 0, 1024 * sizeof(float), stream);

  k_stats<<<2304, 256, 0, stream>>>(x_enc, x_dec, sw1_e, sb1_e, sw1_d, sb1_d,
                                    stats, eav, emx, dav, dmx);
  k_gate <<<B_ * HE_, 256, 0, stream>>>(stats, sw2_e, sb2_e, sw2_d, sb2_d,
                                        eav, emx, dav, dmx,
                                        cw_ea, cb_ea, cw_em, cb_em,
                                        cw_da, cb_da, cw_dm, cb_dm,
                                        cw_f, cb_f, x_enc, out);
}

// Round 4
// 438.684 us; speedup vs baseline: 1.4729x; 1.4729x over previous
//
#include <hip/hip_runtime.h>
#include <math.h>

// Problem constants
static const int B_  = 4;
static const int CE_ = 128;
static const int CD_ = 256;
static const int HE_ = 256;   // = WE
static const int HD_ = 128;   // = WD
static const int N_  = 16;
#define PLANE  65536          // HE*WE = 256*256
#define DPLANE 16384          // HD*WD = 128*128
#define UPSCALE (127.0f/255.0f)

__device__ __forceinline__ float4 fmax4(float4 a, float4 b) {
  return make_float4(fmaxf(a.x, b.x), fmaxf(a.y, b.y), fmaxf(a.z, b.z), fmaxf(a.w, b.w));
}
__device__ __forceinline__ float4 fadd4(float4 a, float4 b) {
  return make_float4(a.x + b.x, a.y + b.y, a.z + b.z, a.w + b.w);
}

// ---------------------------------------------------------------------------
// Phase A: stats kernel, 3584 blocks x 256 threads (round-2 structure).
//   blocks [0,1024)    : enc per-pixel stats — float4, channel loop split
//                        across 4 waves, LDS combine
//   blocks [1024,1536) : enc per-channel stats (float4 grid-stride + reduce)
//   blocks [1536,2560) : dec per-pixel stats — LDS double-buffered row window
//   blocks [2560,3584) : dec per-channel stats (LDS geometry tables)
// ---------------------------------------------------------------------------
__global__ __launch_bounds__(256) void k_stats(
    const float* __restrict__ xe, const float* __restrict__ xd,
    const float* __restrict__ sw1e, const float* __restrict__ sb1e,
    const float* __restrict__ sw1d, const float* __restrict__ sb1d,
    float* __restrict__ stats, float* __restrict__ eav, float* __restrict__ emx,
    float* __restrict__ dav, float* __restrict__ dmx) {
  __shared__ float smem[1024];
  __shared__ float4 red[3][256];   // enc-pixel partials (12 KB)
  int blk = blockIdx.x;
  int t = threadIdx.x;

  if (blk < 1024) {
    // ---- enc per-pixel: block=(b,row); 4 waves x 32 channels; float4 ------
    int b = blk >> 8, h = blk & 255;
    int cs = t >> 6, q = t & 63;     // wave's channel offset, float4 column
    float bias = sb1e[0];
    if (t < CE_) smem[t] = sw1e[t];
    __syncthreads();
    const float4* base = (const float4*)xe + (size_t)b * CE_ * (PLANE / 4)
                         + (size_t)h * 64 + q;
    float4 mx4 = make_float4(-INFINITY, -INFINITY, -INFINITY, -INFINITY);
    float4 sm4 = make_float4(0.f, 0.f, 0.f, 0.f);
    float4 pj4 = make_float4(0.f, 0.f, 0.f, 0.f);
#pragma unroll 4
    for (int c = cs; c < CE_; c += 4) {
      float4 v = base[(size_t)c * (PLANE / 4)];
      float wc = smem[c];
      mx4 = fmax4(mx4, v);
      sm4 = fadd4(sm4, v);
      pj4.x = fmaf(v.x, wc, pj4.x); pj4.y = fmaf(v.y, wc, pj4.y);
      pj4.z = fmaf(v.z, wc, pj4.z); pj4.w = fmaf(v.w, wc, pj4.w);
    }
    red[0][t] = mx4; red[1][t] = sm4; red[2][t] = pj4;
    __syncthreads();
    if (t < 64) {
      float4 m = fmax4(fmax4(red[0][t], red[0][t + 64]),
                       fmax4(red[0][t + 128], red[0][t + 192]));
      float4 s = fadd4(fadd4(red[1][t], red[1][t + 64]),
                       fadd4(red[1][t + 128], red[1][t + 192]));
      float4 p = fadd4(fadd4(red[2][t], red[2][t + 64]),
                       fadd4(red[2][t + 128], red[2][t + 192]));
      float4* so = (float4*)stats;
      size_t o4 = (size_t)(b * 6) * (PLANE / 4) + (size_t)h * 64 + t;
      so[o4] = m;
      s.x *= (1.f / CE_); s.y *= (1.f / CE_); s.z *= (1.f / CE_); s.w *= (1.f / CE_);
      so[o4 + PLANE / 4] = s;
      p.x += bias; p.y += bias; p.z += bias; p.w += bias;
      so[o4 + 2 * (PLANE / 4)] = p;
    }

  } else if (blk < 1536) {
    // ---- enc per-channel: one block per (b,c) ----------------------------
    int bc = blk - 1024;
    const float4* p = (const float4*)(xe + (size_t)bc * PLANE);
    float sm = 0.f, m = -INFINITY;
    for (int i = t; i < PLANE / 4; i += 256) {
      float4 v = p[i];
      sm += (v.x + v.y) + (v.z + v.w);
      m = fmaxf(m, fmaxf(fmaxf(v.x, v.y), fmaxf(v.z, v.w)));
    }
    float* ss = smem;
    float* sx = smem + 256;
    ss[t] = sm; sx[t] = m;
    __syncthreads();
    for (int s = 128; s > 0; s >>= 1) {
      if (t < s) { ss[t] += ss[t + s]; sx[t] = fmaxf(sx[t], sx[t + s]); }
      __syncthreads();
    }
    if (t == 0) { eav[bc] = ss[0] * (1.f / PLANE); emx[bc] = sx[0]; }

  } else if (blk < 2560) {
    // ---- dec per-pixel: LDS-staged row window, double-buffered -----------
    int bh = blk - 1536;
    int b = bh >> 8, h = bh & 255;
    float bias = sb1d[0];
    float* swt  = smem;          // 256 weights
    float* buf0 = smem + 256;    // 256
    float* buf1 = smem + 512;    // 256
    swt[t] = sw1d[t];
    float ph = (float)h * UPSCALE;
    int ih0 = (int)ph; float wh = ph - (float)ih0;
    int ih1 = min(ih0 + 1, HD_ - 1);
    int rowoff = (ih1 - ih0) * HD_;          // 128, or 0 at h=255
    float pw = (float)t * UPSCALE;
    int iw0 = (int)pw; float ww = pw - (float)iw0;
    int iw1 = min(iw0 + 1, HD_ - 1);
    const float* xb = xd + (size_t)b * CD_ * DPLANE + ih0 * HD_;
    int li = min(t, DPLANE - ih0 * HD_ - 1); // clamp window tail at h=255
    float pre = xb[li];
    float mx = -INFINITY, sm = 0.f, pj = 0.f;
    for (int c = 0; c < CD_; ++c) {
      float* bw = (c & 1) ? buf1 : buf0;
      bw[t] = pre;
      if (c + 1 < CD_) pre = xb[(size_t)(c + 1) * DPLANE + li];
      __syncthreads();
      float l00 = bw[iw0], l01 = bw[iw1];
      float l10 = bw[rowoff + iw0], l11 = bw[rowoff + iw1];
      float top = l00 + ww * (l01 - l00);
      float bot = l10 + ww * (l11 - l10);
      float v = fmaxf(top + wh * (bot - top), 0.f);
      mx = fmaxf(mx, v);
      sm += v;
      pj = fmaf(v, swt[c], pj);
    }
    size_t o = (((size_t)b * 6 + 3) * HE_ + h) * (size_t)HE_ + t;
    stats[o] = mx;
    stats[o + (size_t)PLANE] = sm * (1.f / CD_);
    stats[o + 2 * (size_t)PLANE] = pj + bias;

  } else {
    // ---- dec per-channel over virtual upsampled+relu plane ---------------
    int bc = blk - 2560;
    const float* p = xd + (size_t)bc * DPLANE;
    int*   so0  = (int*)smem;
    int*   so1  = so0 + 256;
    float* swht = smem + 512;
    {
      float ph = (float)t * UPSCALE;
      int ih0 = (int)ph;
      so0[t]  = ih0 * HD_;
      so1[t]  = min(ih0 + 1, HD_ - 1) * HD_;
      swht[t] = ph - (float)ih0;
    }
    float pw = (float)t * UPSCALE;
    int iw0 = (int)pw; float ww = pw - (float)iw0;
    int iw1 = min(iw0 + 1, HD_ - 1);
    __syncthreads();
    float sm = 0.f, m = -INFINITY;
#pragma unroll 4
    for (int hh = 0; hh < 256; ++hh) {
      const float* r0 = p + so0[hh];
      const float* r1 = p + so1[hh];
      float wh = swht[hh];
      float top = r0[iw0] * (1.f - ww) + r0[iw1] * ww;
      float bot = r1[iw0] * (1.f - ww) + r1[iw1] * ww;
      float v = fmaxf((1.f - wh) * top + wh * bot, 0.f);
      sm += v;
      m = fmaxf(m, v);
    }
    __syncthreads();   // smem reuse
    float* ss = smem;
    float* sx = smem + 256;
    ss[t] = sm; sx[t] = m;
    __syncthreads();
    for (int s = 128; s > 0; s >>= 1) {
      if (t < s) { ss[t] += ss[t + s]; sx[t] = fmaxf(sx[t], sx[t + s]); }
      __syncthreads();
    }
    if (t == 0) { dav[bc] = ss[0] * (1.f / PLANE); dmx[bc] = sx[0]; }
  }
}

// ---------------------------------------------------------------------------
// Phase B: fused SAG conv + CAG MLP + final gate (round-2, unchanged).
// grid = B*256 blocks (b,row), 256 threads (col).
// ---------------------------------------------------------------------------
__global__ __launch_bounds__(256) void k_gate(
    const float* __restrict__ stats,
    const float* __restrict__ we, const float* __restrict__ be,
    const float* __restrict__ wd, const float* __restrict__ bd,
    const float* __restrict__ eav, const float* __restrict__ emx,
    const float* __restrict__ dav, const float* __restrict__ dmx,
    const float* __restrict__ cw_ea, const float* __restrict__ cb_ea,
    const float* __restrict__ cw_em, const float* __restrict__ cb_em,
    const float* __restrict__ cw_da, const float* __restrict__ cb_da,
    const float* __restrict__ cw_dm, const float* __restrict__ cb_dm,
    const float* __restrict__ cw_f, const float* __restrict__ cb_f,
    const float* __restrict__ x, float* __restrict__ out) {
  int bh = blockIdx.x;
  int b = bh >> 8, h = bh & 255;
  int t = threadIdx.x;
  int w = t;

  __shared__ float swE[147], swD[147];
  __shared__ float part[16][17];   // [n][slice], padded
  __shared__ float s_n[16];
  __shared__ float s_ch[128];
  __shared__ float s_spat[256];

  if (t < 147) { swE[t] = we[t]; swD[t] = wd[t]; }

  // ---- CAG partial dot products: thread t -> (n = t&15, slice = t>>4) ----
  {
    int n = t & 15, sl = t >> 4;
    const float* ea = eav + b * CE_;
    const float* em = emx + b * CE_;
    const float* da = dav + b * CD_;
    const float* dm = dmx + b * CD_;
    float p = 0.f;
#pragma unroll
    for (int i = 0; i < 8; ++i) {
      int c = sl * 8 + i;
      p = fmaf(ea[c], cw_ea[n * CE_ + c], p);
      p = fmaf(em[c], cw_em[n * CE_ + c], p);
    }
#pragma unroll
    for (int i = 0; i < 16; ++i) {
      int c = sl * 16 + i;
      p = fmaf(da[c], cw_da[n * CD_ + c], p);
      p = fmaf(dm[c], cw_dm[n * CD_ + c], p);
    }
    part[n][sl] = p;
  }
  __syncthreads();
  if (t < 16) {
    float s = cb_ea[t] + cb_em[t] + cb_da[t] + cb_dm[t];
#pragma unroll
    for (int sl = 0; sl < 16; ++sl) s += part[t][sl];
    s_n[t] = s;
  }
  __syncthreads();
  if (t < 128) {
    float s = cb_f[t];
#pragma unroll
    for (int n = 0; n < N_; ++n) s = fmaf(s_n[n], cw_f[t * N_ + n], s);
    s_ch[t] = 1.f / (1.f + __expf(-s));
  }

  // ---- SAG dual conv 7x7 over 3 stat channels each -----------------------
  float acc = be[0] + bd[0];
  const float* sb = stats + ((size_t)b * 6) * PLANE;
#pragma unroll
  for (int ic = 0; ic < 3; ++ic) {
    const float* pe = sb + (size_t)ic * PLANE;
    const float* pd = sb + (size_t)(ic + 3) * PLANE;
#pragma unroll
    for (int ky = 0; ky < 7; ++ky) {
      int y = h + ky - 3;
      if ((unsigned)y >= 256u) continue;
      const float* rowE = pe + y * 256;
      const float* rowD = pd + y * 256;
#pragma unroll
      for (int kx = 0; kx < 7; ++kx) {
        int xw = w + kx - 3;
        if ((unsigned)xw >= 256u) continue;
        float we_ = swE[ic * 49 + ky * 7 + kx];
        float wd_ = swD[ic * 49 + ky * 7 + kx];
        acc = fmaf(rowE[xw], we_, acc);
        acc = fmaf(rowD[xw], wd_, acc);
      }
    }
  }
  s_spat[w] = 1.f / (1.f + __expf(-acc));
  __syncthreads();

  // ---- final gate: out = x * spat * ch, float4 IO ------------------------
  int w4 = t & 63;     // float4 index within the 256-wide row
  int cq = t >> 6;     // channel phase 0..3 (wave-uniform)
  float4 sv = ((const float4*)s_spat)[w4];
  const float4* xp = (const float4*)x + ((size_t)b * CE_) * (PLANE / 4) + h * 64;
  float4*       op = (float4*)out     + ((size_t)b * CE_) * (PLANE / 4) + h * 64;
  for (int c = cq; c < CE_; c += 4) {
    float cv = s_ch[c];
    float4 xv = xp[(size_t)c * (PLANE / 4) + w4];
    float4 o;
    o.x = xv.x * sv.x * cv;
    o.y = xv.y * sv.y * cv;
    o.z = xv.z * sv.z * cv;
    o.w = xv.w * sv.w * cv;
    op[(size_t)c * (PLANE / 4) + w4] = o;
  }
}

// ---------------------------------------------------------------------------
extern "C" void kernel_launch(void* const* d_in, const int* in_sizes, int n_in,
                              void* d_out, int out_size, void* d_ws, size_t ws_size,
                              hipStream_t stream) {
  const float* x_enc = (const float*)d_in[0];
  const float* x_dec = (const float*)d_in[1];
  const float* cw_ea = (const float*)d_in[2];
  const float* cb_ea = (const float*)d_in[3];
  const float* cw_em = (const float*)d_in[4];
  const float* cb_em = (const float*)d_in[5];
  const float* cw_da = (const float*)d_in[6];
  const float* cb_da = (const float*)d_in[7];
  const float* cw_dm = (const float*)d_in[8];
  const float* cb_dm = (const float*)d_in[9];
  const float* cw_f  = (const float*)d_in[10];
  const float* cb_f  = (const float*)d_in[11];
  const float* sw1_e = (const float*)d_in[12];
  const float* sb1_e = (const float*)d_in[13];
  const float* sw2_e = (const float*)d_in[14];
  const float* sb2_e = (const float*)d_in[15];
  const float* sw1_d = (const float*)d_in[16];
  const float* sb1_d = (const float*)d_in[17];
  const float* sw2_d = (const float*)d_in[18];
  const float* sb2_d = (const float*)d_in[19];
  float* out = (float*)d_out;
  (void)in_sizes; (void)n_in; (void)out_size; (void)ws_size;

  // workspace layout (floats)
  float* ws    = (float*)d_ws;
  float* stats = ws;                       // B*6*PLANE = 1,572,864
  float* eav   = ws + 1572864;             // B*CE = 512
  float* emx   = eav + 512;                // 512
  float* dav   = emx + 512;                // B*CD = 1024
  float* dmx   = dav + 1024;               // 1024

  k_stats<<<3584, 256, 0, stream>>>(x_enc, x_dec, sw1_e, sb1_e, sw1_d, sb1_d,
                                    stats, eav, emx, dav, dmx);
  k_gate <<<B_ * HE_, 256, 0, stream>>>(stats, sw2_e, sb2_e, sw2_d, sb2_d,
                                        eav, emx, dav, dmx,
                                        cw_ea, cb_ea, cw_em, cb_em,
                                        cw_da, cb_da, cw_dm, cb_dm,
                                        cw_f, cb_f, x_enc, out);
}

// Round 5
// 407.258 us; speedup vs baseline: 1.5866x; 1.0772x over previous
//
#include <hip/hip_runtime.h>
#include <math.h>

// Problem constants
static const int B_  = 4;
static const int CE_ = 128;
static const int CD_ = 256;
static const int HE_ = 256;   // = WE
static const int HD_ = 128;   // = WD
static const int N_  = 16;
#define PLANE  65536          // HE*WE = 256*256
#define DPLANE 16384          // HD*WD = 128*128
#define UPSCALE (127.0f/255.0f)

__device__ __forceinline__ float4 fmax4(float4 a, float4 b) {
  return make_float4(fmaxf(a.x, b.x), fmaxf(a.y, b.y), fmaxf(a.z, b.z), fmaxf(a.w, b.w));
}
__device__ __forceinline__ float4 fadd4(float4 a, float4 b) {
  return make_float4(a.x + b.x, a.y + b.y, a.z + b.z, a.w + b.w);
}

// ---------------------------------------------------------------------------
// Phase A: stats kernel, 3584 blocks x 256 threads.
// Dispatch order puts the serial dec branches FIRST so they co-reside with
// the enc streaming branches instead of running as a trailing phase.
//   blocks [0,1024)    : dec per-pixel stats  (4-channel LDS batches)
//   blocks [1024,2048) : dec per-channel stats (4-phase LDS row-window)
//   blocks [2048,2560) : enc per-channel stats (float4 grid-stride)
//   blocks [2560,3584) : enc per-pixel stats   (float4, 4-wave split)
// ---------------------------------------------------------------------------
__global__ __launch_bounds__(256) void k_stats(
    const float* __restrict__ xe, const float* __restrict__ xd,
    const float* __restrict__ sw1e, const float* __restrict__ sb1e,
    const float* __restrict__ sw1d, const float* __restrict__ sb1d,
    float* __restrict__ stats, float* __restrict__ eav, float* __restrict__ emx,
    float* __restrict__ dav, float* __restrict__ dmx) {
  __shared__ float smem[4864];   // 19 KB overlay, max over branches
  int blk = blockIdx.x;
  int t = threadIdx.x;

  if (blk < 1024) {
    // ---- dec per-pixel: 4 channels per LDS phase, double-buffered --------
    int b = blk >> 8, h = blk & 255;
    float bias = sb1d[0];
    float* swt  = smem;           // 256 weights
    float* bufA = smem + 256;     // 4*256
    float* bufB = smem + 1280;    // 4*256
    swt[t] = sw1d[t];
    float ph = (float)h * UPSCALE;
    int ih0 = (int)ph; float wh = ph - (float)ih0;
    int ih1 = min(ih0 + 1, HD_ - 1);
    int rowoff = (ih1 - ih0) * HD_;          // 128, or 0 at h=255
    float pw = (float)t * UPSCALE;
    int iw0 = (int)pw; float ww = pw - (float)iw0;
    int iw1 = min(iw0 + 1, HD_ - 1);
    const float* xb = xd + (size_t)b * CD_ * DPLANE + ih0 * HD_;
    int li = min(t, DPLANE - ih0 * HD_ - 1); // clamp window tail at h=255
    float pre0 = xb[li];
    float pre1 = xb[DPLANE + li];
    float pre2 = xb[2 * DPLANE + li];
    float pre3 = xb[3 * DPLANE + li];
    float mx = -INFINITY, sm = 0.f, pj = 0.f;
    for (int p = 0; p < 64; ++p) {
      float* bw = (p & 1) ? bufB : bufA;
      bw[t] = pre0; bw[256 + t] = pre1; bw[512 + t] = pre2; bw[768 + t] = pre3;
      if (p + 1 < 64) {
        const float* nx = xb + (size_t)(4 * (p + 1)) * DPLANE;
        pre0 = nx[li];
        pre1 = nx[DPLANE + li];
        pre2 = nx[2 * DPLANE + li];
        pre3 = nx[3 * DPLANE + li];
      }
      __syncthreads();
#pragma unroll
      for (int j = 0; j < 4; ++j) {
        const float* bb = bw + j * 256;
        float l00 = bb[iw0], l01 = bb[iw1];
        float l10 = bb[rowoff + iw0], l11 = bb[rowoff + iw1];
        float top = l00 + ww * (l01 - l00);
        float bot = l10 + ww * (l11 - l10);
        float v = fmaxf(top + wh * (bot - top), 0.f);
        mx = fmaxf(mx, v);
        sm += v;
        pj = fmaf(v, swt[4 * p + j], pj);
      }
    }
    size_t o = (((size_t)b * 6 + 3) * HE_ + h) * (size_t)HE_ + t;
    stats[o] = mx;
    stats[o + (size_t)PLANE] = sm * (1.f / CD_);
    stats[o + 2 * (size_t)PLANE] = pj + bias;

  } else if (blk < 2048) {
    // ---- dec per-channel: 4-phase LDS row-window staging -----------------
    int bc = blk - 1024;
    const float* plane = xd + (size_t)bc * DPLANE;
    float* stage = smem;          // up to 34*128 = 4352
    float* ss = smem + 4352;      // 256
    float* sx = smem + 4608;      // 256
    float pw = (float)t * UPSCALE;
    int iw0 = (int)pw; float ww = pw - (float)iw0;
    int iw1 = min(iw0 + 1, HD_ - 1);
    float sm = 0.f, m = -INFINITY;
    for (int k = 0; k < 4; ++k) {
      int w0   = (k == 0) ? 0 : (32 * k - 1);
      int rend = (k == 3) ? 128 : (32 * (k + 1) + 1);
      int nf = (rend - w0) * HD_;            // <= 4352
      __syncthreads();                       // protect stage from prev readers
      for (int idx = t; idx < nf; idx += 256) stage[idx] = plane[w0 * HD_ + idx];
      __syncthreads();
      int h0 = 64 * k;
#pragma unroll 4
      for (int hh = h0; hh < h0 + 64; ++hh) {
        float ph = (float)hh * UPSCALE;
        int ih0 = (int)ph; float wh = ph - (float)ih0;
        int r0 = (ih0 - w0) * HD_;
        int r1 = (min(ih0 + 1, HD_ - 1) - w0) * HD_;
        float top = stage[r0 + iw0] * (1.f - ww) + stage[r0 + iw1] * ww;
        float bot = stage[r1 + iw0] * (1.f - ww) + stage[r1 + iw1] * ww;
        float v = fmaxf((1.f - wh) * top + wh * bot, 0.f);
        sm += v;
        m = fmaxf(m, v);
      }
    }
    __syncthreads();
    ss[t] = sm; sx[t] = m;
    __syncthreads();
    for (int s = 128; s > 0; s >>= 1) {
      if (t < s) { ss[t] += ss[t + s]; sx[t] = fmaxf(sx[t], sx[t + s]); }
      __syncthreads();
    }
    if (t == 0) { dav[bc] = ss[0] * (1.f / PLANE); dmx[bc] = sx[0]; }

  } else if (blk < 2560) {
    // ---- enc per-channel: one block per (b,c) ----------------------------
    int bc = blk - 2048;
    const float4* p = (const float4*)(xe + (size_t)bc * PLANE);
    float sm = 0.f, m = -INFINITY;
    for (int i = t; i < PLANE / 4; i += 256) {
      float4 v = p[i];
      sm += (v.x + v.y) + (v.z + v.w);
      m = fmaxf(m, fmaxf(fmaxf(v.x, v.y), fmaxf(v.z, v.w)));
    }
    float* ss = smem;
    float* sx = smem + 256;
    ss[t] = sm; sx[t] = m;
    __syncthreads();
    for (int s = 128; s > 0; s >>= 1) {
      if (t < s) { ss[t] += ss[t + s]; sx[t] = fmaxf(sx[t], sx[t + s]); }
      __syncthreads();
    }
    if (t == 0) { eav[bc] = ss[0] * (1.f / PLANE); emx[bc] = sx[0]; }

  } else {
    // ---- enc per-pixel: block=(b,row); 4 waves x 32 channels; float4 -----
    int bh = blk - 2560;
    int b = bh >> 8, h = bh & 255;
    int cs = t >> 6, q = t & 63;     // wave's channel offset, float4 column
    float bias = sb1e[0];
    float*  wt  = smem;              // 128 weights
    float4* red = (float4*)(smem + 128);   // 3*256 float4 partials
    if (t < CE_) wt[t] = sw1e[t];
    __syncthreads();
    const float4* base = (const float4*)xe + (size_t)b * CE_ * (PLANE / 4)
                         + (size_t)h * 64 + q;
    float4 mx4 = make_float4(-INFINITY, -INFINITY, -INFINITY, -INFINITY);
    float4 sm4 = make_float4(0.f, 0.f, 0.f, 0.f);
    float4 pj4 = make_float4(0.f, 0.f, 0.f, 0.f);
#pragma unroll 4
    for (int c = cs; c < CE_; c += 4) {
      float4 v = base[(size_t)c * (PLANE / 4)];
      float wc = wt[c];
      mx4 = fmax4(mx4, v);
      sm4 = fadd4(sm4, v);
      pj4.x = fmaf(v.x, wc, pj4.x); pj4.y = fmaf(v.y, wc, pj4.y);
      pj4.z = fmaf(v.z, wc, pj4.z); pj4.w = fmaf(v.w, wc, pj4.w);
    }
    red[t] = mx4; red[256 + t] = sm4; red[512 + t] = pj4;
    __syncthreads();
    if (t < 64) {
      float4 m = fmax4(fmax4(red[t], red[t + 64]),
                       fmax4(red[t + 128], red[t + 192]));
      float4 s = fadd4(fadd4(red[256 + t], red[256 + t + 64]),
                       fadd4(red[256 + t + 128], red[256 + t + 192]));
      float4 p = fadd4(fadd4(red[512 + t], red[512 + t + 64]),
                       fadd4(red[512 + t + 128], red[512 + t + 192]));
      float4* so = (float4*)stats;
      size_t o4 = (size_t)(b * 6) * (PLANE / 4) + (size_t)h * 64 + t;
      so[o4] = m;
      s.x *= (1.f / CE_); s.y *= (1.f / CE_); s.z *= (1.f / CE_); s.w *= (1.f / CE_);
      so[o4 + PLANE / 4] = s;
      p.x += bias; p.y += bias; p.z += bias; p.w += bias;
      so[o4 + 2 * (PLANE / 4)] = p;
    }
  }
}

// ---------------------------------------------------------------------------
// Phase B: fused SAG conv + CAG MLP + final gate (unchanged).
// grid = B*256 blocks (b,row), 256 threads (col).
// ---------------------------------------------------------------------------
__global__ __launch_bounds__(256) void k_gate(
    const float* __restrict__ stats,
    const float* __restrict__ we, const float* __restrict__ be,
    const float* __restrict__ wd, const float* __restrict__ bd,
    const float* __restrict__ eav, const float* __restrict__ emx,
    const float* __restrict__ dav, const float* __restrict__ dmx,
    const float* __restrict__ cw_ea, const float* __restrict__ cb_ea,
    const float* __restrict__ cw_em, const float* __restrict__ cb_em,
    const float* __restrict__ cw_da, const float* __restrict__ cb_da,
    const float* __restrict__ cw_dm, const float* __restrict__ cb_dm,
    const float* __restrict__ cw_f, const float* __restrict__ cb_f,
    const float* __restrict__ x, float* __restrict__ out) {
  int bh = blockIdx.x;
  int b = bh >> 8, h = bh & 255;
  int t = threadIdx.x;
  int w = t;

  __shared__ float swE[147], swD[147];
  __shared__ float part[16][17];   // [n][slice], padded
  __shared__ float s_n[16];
  __shared__ float s_ch[128];
  __shared__ float s_spat[256];

  if (t < 147) { swE[t] = we[t]; swD[t] = wd[t]; }

  // ---- CAG partial dot products: thread t -> (n = t&15, slice = t>>4) ----
  {
    int n = t & 15, sl = t >> 4;
    const float* ea = eav + b * CE_;
    const float* em = emx + b * CE_;
    const float* da = dav + b * CD_;
    const float* dm = dmx + b * CD_;
    float p = 0.f;
#pragma unroll
    for (int i = 0; i < 8; ++i) {
      int c = sl * 8 + i;
      p = fmaf(ea[c], cw_ea[n * CE_ + c], p);
      p = fmaf(em[c], cw_em[n * CE_ + c], p);
    }
#pragma unroll
    for (int i = 0; i < 16; ++i) {
      int c = sl * 16 + i;
      p = fmaf(da[c], cw_da[n * CD_ + c], p);
      p = fmaf(dm[c], cw_dm[n * CD_ + c], p);
    }
    part[n][sl] = p;
  }
  __syncthreads();
  if (t < 16) {
    float s = cb_ea[t] + cb_em[t] + cb_da[t] + cb_dm[t];
#pragma unroll
    for (int sl = 0; sl < 16; ++sl) s += part[t][sl];
    s_n[t] = s;
  }
  __syncthreads();
  if (t < 128) {
    float s = cb_f[t];
#pragma unroll
    for (int n = 0; n < N_; ++n) s = fmaf(s_n[n], cw_f[t * N_ + n], s);
    s_ch[t] = 1.f / (1.f + __expf(-s));
  }

  // ---- SAG dual conv 7x7 over 3 stat channels each -----------------------
  float acc = be[0] + bd[0];
  const float* sb = stats + ((size_t)b * 6) * PLANE;
#pragma unroll
  for (int ic = 0; ic < 3; ++ic) {
    const float* pe = sb + (size_t)ic * PLANE;
    const float* pd = sb + (size_t)(ic + 3) * PLANE;
#pragma unroll
    for (int ky = 0; ky < 7; ++ky) {
      int y = h + ky - 3;
      if ((unsigned)y >= 256u) continue;
      const float* rowE = pe + y * 256;
      const float* rowD = pd + y * 256;
#pragma unroll
      for (int kx = 0; kx < 7; ++kx) {
        int xw = w + kx - 3;
        if ((unsigned)xw >= 256u) continue;
        float we_ = swE[ic * 49 + ky * 7 + kx];
        float wd_ = swD[ic * 49 + ky * 7 + kx];
        acc = fmaf(rowE[xw], we_, acc);
        acc = fmaf(rowD[xw], wd_, acc);
      }
    }
  }
  s_spat[w] = 1.f / (1.f + __expf(-acc));
  __syncthreads();

  // ---- final gate: out = x * spat * ch, float4 IO ------------------------
  int w4 = t & 63;     // float4 index within the 256-wide row
  int cq = t >> 6;     // channel phase 0..3 (wave-uniform)
  float4 sv = ((const float4*)s_spat)[w4];
  const float4* xp = (const float4*)x + ((size_t)b * CE_) * (PLANE / 4) + h * 64;
  float4*       op = (float4*)out     + ((size_t)b * CE_) * (PLANE / 4) + h * 64;
  for (int c = cq; c < CE_; c += 4) {
    float cv = s_ch[c];
    float4 xv = xp[(size_t)c * (PLANE / 4) + w4];
    float4 o;
    o.x = xv.x * sv.x * cv;
    o.y = xv.y * sv.y * cv;
    o.z = xv.z * sv.z * cv;
    o.w = xv.w * sv.w * cv;
    op[(size_t)c * (PLANE / 4) + w4] = o;
  }
}

// ---------------------------------------------------------------------------
extern "C" void kernel_launch(void* const* d_in, const int* in_sizes, int n_in,
                              void* d_out, int out_size, void* d_ws, size_t ws_size,
                              hipStream_t stream) {
  const float* x_enc = (const float*)d_in[0];
  const float* x_dec = (const float*)d_in[1];
  const float* cw_ea = (const float*)d_in[2];
  const float* cb_ea = (const float*)d_in[3];
  const float* cw_em = (const float*)d_in[4];
  const float* cb_em = (const float*)d_in[5];
  const float* cw_da = (const float*)d_in[6];
  const float* cb_da = (const float*)d_in[7];
  const float* cw_dm = (const float*)d_in[8];
  const float* cb_dm = (const float*)d_in[9];
  const float* cw_f  = (const float*)d_in[10];
  const float* cb_f  = (const float*)d_in[11];
  const float* sw1_e = (const float*)d_in[12];
  const float* sb1_e = (const float*)d_in[13];
  const float* sw2_e = (const float*)d_in[14];
  const float* sb2_e = (const float*)d_in[15];
  const float* sw1_d = (const float*)d_in[16];
  const float* sb1_d = (const float*)d_in[17];
  const float* sw2_d = (const float*)d_in[18];
  const float* sb2_d = (const float*)d_in[19];
  float* out = (float*)d_out;
  (void)in_sizes; (void)n_in; (void)out_size; (void)ws_size;

  // workspace layout (floats)
  float* ws    = (float*)d_ws;
  float* stats = ws;                       // B*6*PLANE = 1,572,864
  float* eav   = ws + 1572864;             // B*CE = 512
  float* emx   = eav + 512;                // 512
  float* dav   = emx + 512;                // B*CD = 1024
  float* dmx   = dav + 1024;               // 1024

  k_stats<<<3584, 256, 0, stream>>>(x_enc, x_dec, sw1_e, sb1_e, sw1_d, sb1_d,
                                    stats, eav, emx, dav, dmx);
  k_gate <<<B_ * HE_, 256, 0, stream>>>(stats, sw2_e, sb2_e, sw2_d, sb2_d,
                                        eav, emx, dav, dmx,
                                        cw_ea, cb_ea, cw_em, cb_em,
                                        cw_da, cb_da, cw_dm, cb_dm,
                                        cw_f, cb_f, x_enc, out);
}